// Round 3
// baseline (330.722 us; speedup 1.0000x reference)
//
#include <hip/hip_runtime.h>
#include <math.h>

#define N 4096
#define D 512
#define MARGIN 0.05f
#define L2_REG 0.02f
#define N_POS 3
#define NCLASS 100
#define MAXC 256          // max members per class (expected ~41 +/- 7)
#define MAXPAIRS (3 * N)

#define BM 128
#define BN 128
#define BK 64
#define NT (N / BM)       // 32 tiles per dim

typedef unsigned short u16;
typedef __attribute__((ext_vector_type(8))) short bf16x8;
typedef __attribute__((ext_vector_type(8))) unsigned short u16x8;
typedef __attribute__((ext_vector_type(4))) float f32x4;

__device__ __forceinline__ u16 f2bf(float f) {
    unsigned u = __builtin_bit_cast(unsigned, f);
    unsigned r = u + 0x7fffu + ((u >> 16) & 1u);   // round-to-nearest-even
    return (u16)(r >> 16);
}

// ---------- kernel A: f32->bf16 convert + row sq-norms + sum of norms ----------
__global__ __launch_bounds__(256)
void prep(const float* __restrict__ X, u16* __restrict__ Xb,
          float* __restrict__ sqn, float* __restrict__ norm_sum) {
    int row  = blockIdx.x * 4 + (threadIdx.x >> 6);
    int lane = threadIdx.x & 63;
    const float* xr = X + (size_t)row * D + lane * 8;
    float4 v0 = *reinterpret_cast<const float4*>(xr);
    float4 v1 = *reinterpret_cast<const float4*>(xr + 4);
    u16x8 o;
    o[0] = f2bf(v0.x); o[1] = f2bf(v0.y); o[2] = f2bf(v0.z); o[3] = f2bf(v0.w);
    o[4] = f2bf(v1.x); o[5] = f2bf(v1.y); o[6] = f2bf(v1.z); o[7] = f2bf(v1.w);
    *reinterpret_cast<u16x8*>(Xb + (size_t)row * D + lane * 8) = o;
    float s = v0.x * v0.x + v0.y * v0.y + v0.z * v0.z + v0.w * v0.w
            + v1.x * v1.x + v1.y * v1.y + v1.z * v1.z + v1.w * v1.w;
    #pragma unroll
    for (int off = 32; off; off >>= 1) s += __shfl_xor(s, off);
    if (lane == 0) {
        sqn[row] = s;
        atomicAdd(norm_sum, sqrtf(s));
    }
}

// ---------- kernel B: per-class ordered member list -> first-3 pair emission ----------
__global__ __launch_bounds__(256)
void build_pairs(const int* __restrict__ tgt, int2* __restrict__ pairs,
                 int* __restrict__ pair_count) {
    const int c = blockIdx.x;
    const int t = threadIdx.x;
    __shared__ int idxs[MAXC];
    __shared__ int cnt;
    __shared__ int woff[4], wbase[4];
    if (t == 0) cnt = 0;
    __syncthreads();

    for (int j0 = 0; j0 < N; j0 += 256) {
        int j = j0 + t;
        bool m = (tgt[j] == c);
        unsigned long long bal = __ballot(m);
        if ((t & 63) == 0) woff[t >> 6] = __popcll(bal);
        __syncthreads();
        if (t == 0) {
            int s = cnt;
            #pragma unroll
            for (int w = 0; w < 4; ++w) { wbase[w] = s; s += woff[w]; }
            cnt = s;
        }
        __syncthreads();
        if (m) {
            int lane = t & 63;
            int pos = wbase[t >> 6] + __popcll(bal & ((1ull << lane) - 1ull));
            if (pos < MAXC) idxs[pos] = j;
        }
        __syncthreads();
    }

    int n = cnt < MAXC ? cnt : MAXC;
    for (int p = t; p < n; p += 256) {
        #pragma unroll
        for (int q = 1; q <= N_POS; ++q) {
            if (p + q < n) {
                int slot = atomicAdd(pair_count, 1);
                pairs[slot] = make_int2(idxs[p], idxs[p + q]);
            }
        }
    }
}

// ---------- kernel C: triangular MFMA X.X^T + fused dist/exp/mask, row+col reduce ----------
__global__ __launch_bounds__(256)
void lneg_mfma(const u16* __restrict__ Xb, const int* __restrict__ tgt,
               const float* __restrict__ sqn, float* __restrict__ l_n) {
    // triangular tile index: z -> (bi, bj), bi <= bj
    int z = blockIdx.x;
    int bi = (int)((2 * NT + 1 - sqrtf((float)((2 * NT + 1) * (2 * NT + 1)) - 8.0f * (float)z)) * 0.5f);
    while (z <  bi * (2 * NT + 1 - bi) / 2) --bi;
    while (z >= (bi + 1) * (2 * NT - bi) / 2) ++bi;
    const int bj = bi + (z - bi * (2 * NT + 1 - bi) / 2);
    const int row0 = bi * BM, col0 = bj * BN;
    const bool offdiag = (bi != bj);

    // LDS: 16B chunk index c = kq*128 + row  (kq = k-octet 0..7, row 0..127)
    __shared__ u16 As[(BK / 8) * BM * 8];   // 16 KB
    __shared__ u16 Bs[(BK / 8) * BN * 8];   // 16 KB
    const int t = threadIdx.x;
    const int w = t >> 6, l = t & 63;
    const int wr = w >> 1, wc = w & 1;       // wave quadrant: 64x64 output
    const int lc = l & 15, lg = l >> 4;

    f32x4 acc[4][4] = {};

    for (int k0 = 0; k0 < D; k0 += BK) {
        #pragma unroll
        for (int q = 0; q < 4; ++q) {
            int c = w * 256 + q * 64 + l;
            int row = c & 127, kq = c >> 7;
            const u16* ga = Xb + (size_t)(row0 + row) * D + k0 + kq * 8;
            const u16* gb = Xb + (size_t)(col0 + row) * D + k0 + kq * 8;
            u16* la = As + (size_t)(w * 256 + q * 64) * 8;   // wave-uniform base; HW adds lane*16
            u16* lb = Bs + (size_t)(w * 256 + q * 64) * 8;
            __builtin_amdgcn_global_load_lds((const __attribute__((address_space(1))) unsigned int*)ga,
                                             (__attribute__((address_space(3))) unsigned int*)la, 16, 0, 0);
            __builtin_amdgcn_global_load_lds((const __attribute__((address_space(1))) unsigned int*)gb,
                                             (__attribute__((address_space(3))) unsigned int*)lb, 16, 0, 0);
        }
        __syncthreads();   // drains vmcnt before ds_read

        bf16x8 af[4][2], bfr[4][2];
        #pragma unroll
        for (int fm = 0; fm < 4; ++fm)
            #pragma unroll
            for (int ks = 0; ks < 2; ++ks) {
                int row = wr * 64 + fm * 16 + lc;
                int kq  = ks * 4 + lg;
                af[fm][ks] = *reinterpret_cast<const bf16x8*>(As + (size_t)(kq * BM + row) * 8);
            }
        #pragma unroll
        for (int fn = 0; fn < 4; ++fn)
            #pragma unroll
            for (int ks = 0; ks < 2; ++ks) {
                int col = wc * 64 + fn * 16 + lc;
                int kq  = ks * 4 + lg;
                bfr[fn][ks] = *reinterpret_cast<const bf16x8*>(Bs + (size_t)(kq * BN + col) * 8);
            }
        #pragma unroll
        for (int fm = 0; fm < 4; ++fm)
            #pragma unroll
            for (int fn = 0; fn < 4; ++fn) {
                acc[fm][fn] = __builtin_amdgcn_mfma_f32_16x16x32_bf16(af[fm][0], bfr[fn][0], acc[fm][fn], 0, 0, 0);
                acc[fm][fn] = __builtin_amdgcn_mfma_f32_16x16x32_bf16(af[fm][1], bfr[fn][1], acc[fm][fn], 0, 0, 0);
            }
        __syncthreads();   // protect LDS before next stage
    }

    // epilogue: C layout col = l&15, row = (l>>4)*4 + reg  [guide m89]
    int tgj[4]; float sqj[4];
    #pragma unroll
    for (int fn = 0; fn < 4; ++fn) {
        int gj = col0 + wc * 64 + fn * 16 + lc;
        tgj[fn] = tgt[gj]; sqj[fn] = sqn[gj];
    }
    float csum[4] = {};
    #pragma unroll
    for (int fm = 0; fm < 4; ++fm) {
        #pragma unroll
        for (int r = 0; r < 4; ++r) {
            int gi = row0 + wr * 64 + fm * 16 + lg * 4 + r;
            float sqi = sqn[gi]; int tgi = tgt[gi];
            float rs = 0.f;
            #pragma unroll
            for (int fn = 0; fn < 4; ++fn) {
                float sq = sqi + sqj[fn] - 2.f * acc[fm][fn][r];
                sq = fmaxf(sq, 0.f);
                float dd = sq > 1e-12f ? sqrtf(sq) : 0.f;
                float e = (tgi != tgj[fn]) ? __expf(MARGIN - dd) : 0.f;
                rs += e;
                csum[fn] += e;
            }
            // 16 lanes (same lg) share this row
            rs += __shfl_xor(rs, 1); rs += __shfl_xor(rs, 2);
            rs += __shfl_xor(rs, 4); rs += __shfl_xor(rs, 8);
            if (lc == 0) atomicAdd(&l_n[gi], rs);
        }
    }
    if (offdiag) {
        // column sums: reduce across lg groups (lanes with same lc)
        #pragma unroll
        for (int fn = 0; fn < 4; ++fn) {
            float s = csum[fn];
            s += __shfl_xor(s, 16); s += __shfl_xor(s, 32);
            if (lg == 0) atomicAdd(&l_n[col0 + wc * 64 + fn * 16 + lc], s);
        }
    }
}

// ---------- kernel D: one wave per positive pair -> pair loss ----------
__global__ __launch_bounds__(256)
void pair_loss(const float* __restrict__ X, const float* __restrict__ sqn,
               const float* __restrict__ l_n, const int2* __restrict__ pairs,
               const int* __restrict__ pair_count, float* __restrict__ pair_sum) {
    int wid  = (blockIdx.x * 256 + threadIdx.x) >> 6;
    int lane = threadIdx.x & 63;
    if (wid >= *pair_count) return;
    int2 pr = pairs[wid];
    const float* xi = X + (size_t)pr.x * D + lane * 8;
    const float* xj = X + (size_t)pr.y * D + lane * 8;
    float4 a0 = *reinterpret_cast<const float4*>(xi);
    float4 a1 = *reinterpret_cast<const float4*>(xi + 4);
    float4 b0 = *reinterpret_cast<const float4*>(xj);
    float4 b1 = *reinterpret_cast<const float4*>(xj + 4);
    float s = a0.x * b0.x + a0.y * b0.y + a0.z * b0.z + a0.w * b0.w
            + a1.x * b1.x + a1.y * b1.y + a1.z * b1.z + a1.w * b1.w;
    #pragma unroll
    for (int off = 32; off; off >>= 1) s += __shfl_xor(s, off);
    if (lane == 0) {
        float sq = sqn[pr.x] + sqn[pr.y] - 2.f * s;
        sq = fmaxf(sq, 0.f);
        float dd = sq > 1e-12f ? sqrtf(sq) : 0.f;
        float ln = logf(l_n[pr.x] + l_n[pr.y]);
        float pl = fmaxf(ln + dd, 0.f);
        atomicAdd(pair_sum, pl * pl);
    }
}

// ---------- kernel E: finalize scalar ----------
__global__ void finalize(const float* __restrict__ pair_sum, const int* __restrict__ pair_count,
                         const float* __restrict__ norm_sum, float* __restrict__ out) {
    out[0] = pair_sum[0] / (float)pair_count[0] + L2_REG * norm_sum[0] / (float)N;
}

extern "C" void kernel_launch(void* const* d_in, const int* in_sizes, int n_in,
                              void* d_out, int out_size, void* d_ws, size_t ws_size,
                              hipStream_t stream) {
    const float* X   = (const float*)d_in[0];
    const int*   tgt = (const int*)d_in[1];

    u16*   Xb = (u16*)d_ws;                                   // N*D bf16 = 4 MB
    float* fw = (float*)((char*)d_ws + (size_t)N * D * 2);
    float* sqn        = fw;                // N
    float* l_n        = fw + N;            // N
    float* norm_sum   = fw + 2 * N;        // 1
    float* pair_sum   = fw + 2 * N + 1;    // 1
    int*   pair_count = (int*)(fw + 2 * N + 2);
    int2*  pairs      = (int2*)(fw + 2 * N + 4);              // MAXPAIRS int2

    // zero l_n .. pair_count (ws is poisoned 0xAA before every call)
    hipMemsetAsync(l_n, 0, (N + 3) * sizeof(float), stream);

    prep<<<N / 4, 256, 0, stream>>>(X, Xb, sqn, norm_sum);
    build_pairs<<<NCLASS, 256, 0, stream>>>(tgt, pairs, pair_count);
    lneg_mfma<<<NT * (NT + 1) / 2, 256, 0, stream>>>(Xb, tgt, sqn, l_n);
    pair_loss<<<(MAXPAIRS * 64) / 256, 256, 0, stream>>>(X, sqn, l_n, pairs, pair_count, pair_sum);
    finalize<<<1, 1, 0, stream>>>(pair_sum, pair_count, norm_sum, (float*)d_out);
}

// Round 4
// 143.129 us; speedup vs baseline: 2.3107x; 2.3107x over previous
//
#include <hip/hip_runtime.h>
#include <math.h>

#define N 4096
#define D 512
#define MARGIN 0.05f
#define L2_REG 0.02f
#define N_POS 3
#define NCLASS 100
#define MAXC 256          // max members per class (expected ~41 +/- 7)
#define MAXPAIRS (3 * N)

#define BM 128
#define BN 128
#define BK 64
#define NT (N / BM)       // 32 tiles per dim

typedef unsigned short u16;
typedef __attribute__((ext_vector_type(8))) short bf16x8;
typedef __attribute__((ext_vector_type(8))) unsigned short u16x8;
typedef __attribute__((ext_vector_type(4))) float f32x4;

__device__ __forceinline__ u16 f2bf(float f) {
    unsigned u = __builtin_bit_cast(unsigned, f);
    unsigned r = u + 0x7fffu + ((u >> 16) & 1u);   // round-to-nearest-even
    return (u16)(r >> 16);
}

// ---------- kernel A: f32->bf16 convert + row sq-norms + per-row norm ----------
__global__ __launch_bounds__(256)
void prep(const float* __restrict__ X, u16* __restrict__ Xb,
          float* __restrict__ sqn, float* __restrict__ rown) {
    int row  = blockIdx.x * 4 + (threadIdx.x >> 6);
    int lane = threadIdx.x & 63;
    const float* xr = X + (size_t)row * D + lane * 8;
    float4 v0 = *reinterpret_cast<const float4*>(xr);
    float4 v1 = *reinterpret_cast<const float4*>(xr + 4);
    u16x8 o;
    o[0] = f2bf(v0.x); o[1] = f2bf(v0.y); o[2] = f2bf(v0.z); o[3] = f2bf(v0.w);
    o[4] = f2bf(v1.x); o[5] = f2bf(v1.y); o[6] = f2bf(v1.z); o[7] = f2bf(v1.w);
    *reinterpret_cast<u16x8*>(Xb + (size_t)row * D + lane * 8) = o;
    float s = v0.x * v0.x + v0.y * v0.y + v0.z * v0.z + v0.w * v0.w
            + v1.x * v1.x + v1.y * v1.y + v1.z * v1.z + v1.w * v1.w;
    #pragma unroll
    for (int off = 32; off; off >>= 1) s += __shfl_xor(s, off);
    if (lane == 0) {
        sqn[row]  = s;
        rown[row] = sqrtf(s);
    }
}

// ---------- kernel B: per-class member list -> first-3 pairs, 1 atomic/class ----------
__global__ __launch_bounds__(256)
void build_pairs(const int* __restrict__ tgt, int2* __restrict__ pairs,
                 int* __restrict__ pair_count) {
    const int c = blockIdx.x;
    const int t = threadIdx.x;
    __shared__ int idxs[MAXC];
    __shared__ int cnt;
    __shared__ int base;
    __shared__ int woff[4], wbase[4];
    if (t == 0) cnt = 0;
    __syncthreads();

    for (int j0 = 0; j0 < N; j0 += 256) {
        int j = j0 + t;
        bool m = (tgt[j] == c);
        unsigned long long bal = __ballot(m);
        if ((t & 63) == 0) woff[t >> 6] = __popcll(bal);
        __syncthreads();
        if (t == 0) {
            int s = cnt;
            #pragma unroll
            for (int w = 0; w < 4; ++w) { wbase[w] = s; s += woff[w]; }
            cnt = s;
        }
        __syncthreads();
        if (m) {
            int lane = t & 63;
            int pos = wbase[t >> 6] + __popcll(bal & ((1ull << lane) - 1ull));
            if (pos < MAXC) idxs[pos] = j;
        }
        __syncthreads();
    }

    const int n  = cnt < MAXC ? cnt : MAXC;
    const int n1 = n - 1 > 0 ? n - 1 : 0;
    const int n2 = n - 2 > 0 ? n - 2 : 0;
    const int n3 = n - 3 > 0 ? n - 3 : 0;
    if (t == 0) base = atomicAdd(pair_count, n1 + n2 + n3);   // one reservation per class
    __syncthreads();
    const int b = base;
    for (int p = t; p < n1; p += 256) pairs[b + p]           = make_int2(idxs[p], idxs[p + 1]);
    for (int p = t; p < n2; p += 256) pairs[b + n1 + p]      = make_int2(idxs[p], idxs[p + 2]);
    for (int p = t; p < n3; p += 256) pairs[b + n1 + n2 + p] = make_int2(idxs[p], idxs[p + 3]);
}

// ---------- kernel C: triangular MFMA X.X^T + fused dist/exp/mask, row+col reduce ----------
__global__ __launch_bounds__(256)
void lneg_mfma(const u16* __restrict__ Xb, const int* __restrict__ tgt,
               const float* __restrict__ sqn, float* __restrict__ l_n) {
    // triangular tile index: z -> (bi, bj), bi <= bj
    int z = blockIdx.x;
    int bi = (int)((2 * NT + 1 - sqrtf((float)((2 * NT + 1) * (2 * NT + 1)) - 8.0f * (float)z)) * 0.5f);
    while (z <  bi * (2 * NT + 1 - bi) / 2) --bi;
    while (z >= (bi + 1) * (2 * NT - bi) / 2) ++bi;
    const int bj = bi + (z - bi * (2 * NT + 1 - bi) / 2);
    const int row0 = bi * BM, col0 = bj * BN;
    const bool offdiag = (bi != bj);

    // LDS: 16B chunk index c = kq*128 + row  (kq = k-octet 0..7, row 0..127)
    __shared__ u16 As[(BK / 8) * BM * 8];   // 16 KB
    __shared__ u16 Bs[(BK / 8) * BN * 8];   // 16 KB
    const int t = threadIdx.x;
    const int w = t >> 6, l = t & 63;
    const int wr = w >> 1, wc = w & 1;       // wave quadrant: 64x64 output
    const int lc = l & 15, lg = l >> 4;

    f32x4 acc[4][4] = {};

    for (int k0 = 0; k0 < D; k0 += BK) {
        #pragma unroll
        for (int q = 0; q < 4; ++q) {
            int c = w * 256 + q * 64 + l;
            int row = c & 127, kq = c >> 7;
            const u16* ga = Xb + (size_t)(row0 + row) * D + k0 + kq * 8;
            const u16* gb = Xb + (size_t)(col0 + row) * D + k0 + kq * 8;
            u16* la = As + (size_t)(w * 256 + q * 64) * 8;   // wave-uniform base; HW adds lane*16
            u16* lb = Bs + (size_t)(w * 256 + q * 64) * 8;
            __builtin_amdgcn_global_load_lds((const __attribute__((address_space(1))) unsigned int*)ga,
                                             (__attribute__((address_space(3))) unsigned int*)la, 16, 0, 0);
            __builtin_amdgcn_global_load_lds((const __attribute__((address_space(1))) unsigned int*)gb,
                                             (__attribute__((address_space(3))) unsigned int*)lb, 16, 0, 0);
        }
        __syncthreads();   // drains vmcnt before ds_read

        bf16x8 af[4][2], bfr[4][2];
        #pragma unroll
        for (int fm = 0; fm < 4; ++fm)
            #pragma unroll
            for (int ks = 0; ks < 2; ++ks) {
                int row = wr * 64 + fm * 16 + lc;
                int kq  = ks * 4 + lg;
                af[fm][ks] = *reinterpret_cast<const bf16x8*>(As + (size_t)(kq * BM + row) * 8);
            }
        #pragma unroll
        for (int fn = 0; fn < 4; ++fn)
            #pragma unroll
            for (int ks = 0; ks < 2; ++ks) {
                int col = wc * 64 + fn * 16 + lc;
                int kq  = ks * 4 + lg;
                bfr[fn][ks] = *reinterpret_cast<const bf16x8*>(Bs + (size_t)(kq * BN + col) * 8);
            }
        #pragma unroll
        for (int fm = 0; fm < 4; ++fm)
            #pragma unroll
            for (int fn = 0; fn < 4; ++fn) {
                acc[fm][fn] = __builtin_amdgcn_mfma_f32_16x16x32_bf16(af[fm][0], bfr[fn][0], acc[fm][fn], 0, 0, 0);
                acc[fm][fn] = __builtin_amdgcn_mfma_f32_16x16x32_bf16(af[fm][1], bfr[fn][1], acc[fm][fn], 0, 0, 0);
            }
        __syncthreads();   // protect LDS before next stage
    }

    // epilogue: C layout col = l&15, row = (l>>4)*4 + reg  [guide m89]
    int tgj[4]; float sqj[4];
    #pragma unroll
    for (int fn = 0; fn < 4; ++fn) {
        int gj = col0 + wc * 64 + fn * 16 + lc;
        tgj[fn] = tgt[gj]; sqj[fn] = sqn[gj];
    }
    float csum[4] = {};
    #pragma unroll
    for (int fm = 0; fm < 4; ++fm) {
        #pragma unroll
        for (int r = 0; r < 4; ++r) {
            int gi = row0 + wr * 64 + fm * 16 + lg * 4 + r;
            float sqi = sqn[gi]; int tgi = tgt[gi];
            float rs = 0.f;
            #pragma unroll
            for (int fn = 0; fn < 4; ++fn) {
                float sq = sqi + sqj[fn] - 2.f * acc[fm][fn][r];
                sq = fmaxf(sq, 0.f);
                float dd = sq > 1e-12f ? sqrtf(sq) : 0.f;
                float e = (tgi != tgj[fn]) ? __expf(MARGIN - dd) : 0.f;
                rs += e;
                csum[fn] += e;
            }
            // 16 lanes (same lg) share this row
            rs += __shfl_xor(rs, 1); rs += __shfl_xor(rs, 2);
            rs += __shfl_xor(rs, 4); rs += __shfl_xor(rs, 8);
            if (lc == 0) atomicAdd(&l_n[gi], rs);
        }
    }
    if (offdiag) {
        // column sums: reduce across lg groups (lanes with same lc)
        #pragma unroll
        for (int fn = 0; fn < 4; ++fn) {
            float s = csum[fn];
            s += __shfl_xor(s, 16); s += __shfl_xor(s, 32);
            if (lg == 0) atomicAdd(&l_n[col0 + wc * 64 + fn * 16 + lc], s);
        }
    }
}

// ---------- kernel D: grid-stride pair loss, 1 atomic per block ----------
#define PL_BLOCKS 256
__global__ __launch_bounds__(256)
void pair_loss(const float* __restrict__ X, const float* __restrict__ sqn,
               const float* __restrict__ l_n, const int2* __restrict__ pairs,
               const int* __restrict__ pair_count, float* __restrict__ pair_sum) {
    const int t = threadIdx.x;
    const int lane = t & 63;
    const int np = *pair_count;
    const int wid0 = blockIdx.x * 4 + (t >> 6);
    float local = 0.f;
    for (int p = wid0; p < np; p += PL_BLOCKS * 4) {
        int2 pr = pairs[p];
        const float* xi = X + (size_t)pr.x * D + lane * 8;
        const float* xj = X + (size_t)pr.y * D + lane * 8;
        float4 a0 = *reinterpret_cast<const float4*>(xi);
        float4 a1 = *reinterpret_cast<const float4*>(xi + 4);
        float4 b0 = *reinterpret_cast<const float4*>(xj);
        float4 b1 = *reinterpret_cast<const float4*>(xj + 4);
        float s = a0.x * b0.x + a0.y * b0.y + a0.z * b0.z + a0.w * b0.w
                + a1.x * b1.x + a1.y * b1.y + a1.z * b1.z + a1.w * b1.w;
        #pragma unroll
        for (int off = 32; off; off >>= 1) s += __shfl_xor(s, off);
        if (lane == 0) {
            float sq = sqn[pr.x] + sqn[pr.y] - 2.f * s;
            sq = fmaxf(sq, 0.f);
            float dd = sq > 1e-12f ? sqrtf(sq) : 0.f;
            float ln = logf(l_n[pr.x] + l_n[pr.y]);
            float pl = fmaxf(ln + dd, 0.f);
            local += pl * pl;
        }
    }
    __shared__ float wsum[4];
    if (lane == 0) wsum[t >> 6] = local;
    __syncthreads();
    if (t == 0) atomicAdd(pair_sum, wsum[0] + wsum[1] + wsum[2] + wsum[3]);
}

// ---------- kernel E: finalize — reduce row norms + combine scalars ----------
__global__ __launch_bounds__(256)
void finalize(const float* __restrict__ rown, const float* __restrict__ pair_sum,
              const int* __restrict__ pair_count, float* __restrict__ out) {
    const int t = threadIdx.x;
    float s = 0.f;
    for (int i = t; i < N; i += 256) s += rown[i];
    #pragma unroll
    for (int off = 32; off; off >>= 1) s += __shfl_xor(s, off);
    __shared__ float wsum[4];
    if ((t & 63) == 0) wsum[t >> 6] = s;
    __syncthreads();
    if (t == 0) {
        float norm_sum = wsum[0] + wsum[1] + wsum[2] + wsum[3];
        out[0] = pair_sum[0] / (float)pair_count[0] + L2_REG * norm_sum / (float)N;
    }
}

extern "C" void kernel_launch(void* const* d_in, const int* in_sizes, int n_in,
                              void* d_out, int out_size, void* d_ws, size_t ws_size,
                              hipStream_t stream) {
    const float* X   = (const float*)d_in[0];
    const int*   tgt = (const int*)d_in[1];

    u16*   Xb = (u16*)d_ws;                                   // N*D bf16 = 4 MB
    float* fw = (float*)((char*)d_ws + (size_t)N * D * 2);
    float* sqn        = fw;                // N
    float* rown       = fw + N;            // N
    float* l_n        = fw + 2 * N;        // N
    float* pair_sum   = fw + 3 * N;        // 1
    int*   pair_count = (int*)(fw + 3 * N + 1);
    int2*  pairs      = (int2*)(fw + 3 * N + 2);              // MAXPAIRS int2

    // zero l_n, pair_sum, pair_count (ws is poisoned 0xAA before every call)
    hipMemsetAsync(l_n, 0, (N + 2) * sizeof(float), stream);

    prep<<<N / 4, 256, 0, stream>>>(X, Xb, sqn, rown);
    build_pairs<<<NCLASS, 256, 0, stream>>>(tgt, pairs, pair_count);
    lneg_mfma<<<NT * (NT + 1) / 2, 256, 0, stream>>>(Xb, tgt, sqn, l_n);
    pair_loss<<<PL_BLOCKS, 256, 0, stream>>>(X, sqn, l_n, pairs, pair_count, pair_sum);
    finalize<<<1, 256, 0, stream>>>(rown, pair_sum, pair_count, (float*)d_out);
}

// Round 6
// 125.717 us; speedup vs baseline: 2.6307x; 1.1385x over previous
//
#include <hip/hip_runtime.h>
#include <math.h>

#define N 4096
#define D 512
#define MARGIN 0.05f
#define L2_REG 0.02f
#define N_POS 3
#define NCLASS 100
#define MAXC 256          // max members per class (expected ~41 +/- 7)
#define MAXPAIRS (3 * N)

#define BM 128
#define BN 128
#define BK 64
#define NT (N / BM)       // 32 tiles per dim

typedef unsigned short u16;
typedef __attribute__((ext_vector_type(8))) short bf16x8;
typedef __attribute__((ext_vector_type(8))) unsigned short u16x8;
typedef __attribute__((ext_vector_type(4))) float f32x4;

__device__ __forceinline__ u16 f2bf(float f) {
    unsigned u = __builtin_bit_cast(unsigned, f);
    unsigned r = u + 0x7fffu + ((u >> 16) & 1u);   // round-to-nearest-even
    return (u16)(r >> 16);
}

// ---------- kernel A: f32->bf16 convert + row sq-norms + init accumulators ----------
__global__ __launch_bounds__(256)
void prep(const float* __restrict__ X, u16* __restrict__ Xb,
          float* __restrict__ sqn, float* __restrict__ rown,
          float* __restrict__ l_n, int* __restrict__ pair_count) {
    int row  = blockIdx.x * 4 + (threadIdx.x >> 6);
    int lane = threadIdx.x & 63;
    const float* xr = X + (size_t)row * D + lane * 8;
    float4 v0 = *reinterpret_cast<const float4*>(xr);
    float4 v1 = *reinterpret_cast<const float4*>(xr + 4);
    u16x8 o;
    o[0] = f2bf(v0.x); o[1] = f2bf(v0.y); o[2] = f2bf(v0.z); o[3] = f2bf(v0.w);
    o[4] = f2bf(v1.x); o[5] = f2bf(v1.y); o[6] = f2bf(v1.z); o[7] = f2bf(v1.w);
    *reinterpret_cast<u16x8*>(Xb + (size_t)row * D + lane * 8) = o;
    float s = v0.x * v0.x + v0.y * v0.y + v0.z * v0.z + v0.w * v0.w
            + v1.x * v1.x + v1.y * v1.y + v1.z * v1.z + v1.w * v1.w;
    #pragma unroll
    for (int off = 32; off; off >>= 1) s += __shfl_xor(s, off);
    if (lane == 0) {
        sqn[row]  = s;
        rown[row] = sqrtf(s);
    }
    // zero-init accumulators (ws is poisoned 0xAA before every call)
    if (threadIdx.x < 4) l_n[blockIdx.x * 4 + threadIdx.x] = 0.f;
    if (blockIdx.x == 0 && threadIdx.x == 0) *pair_count = 0;
}

// ---------- kernel B: per-class member list -> first-3 pairs, 1 atomic/class ----------
__global__ __launch_bounds__(256)
void build_pairs(const int* __restrict__ tgt, int2* __restrict__ pairs,
                 int* __restrict__ pair_count, float* __restrict__ out) {
    const int c = blockIdx.x;
    const int t = threadIdx.x;
    __shared__ int idxs[MAXC];
    __shared__ int cnt;
    __shared__ int base;
    __shared__ int woff[4], wbase[4];
    if (c == 0 && t == 0) out[0] = 0.f;    // out accumulated by pair_loss later
    if (t == 0) cnt = 0;
    __syncthreads();

    for (int j0 = 0; j0 < N; j0 += 256) {
        int j = j0 + t;
        bool m = (tgt[j] == c);
        unsigned long long bal = __ballot(m);
        if ((t & 63) == 0) woff[t >> 6] = __popcll(bal);
        __syncthreads();
        if (t == 0) {
            int s = cnt;
            #pragma unroll
            for (int w = 0; w < 4; ++w) { wbase[w] = s; s += woff[w]; }
            cnt = s;
        }
        __syncthreads();
        if (m) {
            int lane = t & 63;
            int pos = wbase[t >> 6] + __popcll(bal & ((1ull << lane) - 1ull));
            if (pos < MAXC) idxs[pos] = j;
        }
        __syncthreads();
    }

    const int n  = cnt < MAXC ? cnt : MAXC;
    const int n1 = n - 1 > 0 ? n - 1 : 0;
    const int n2 = n - 2 > 0 ? n - 2 : 0;
    const int n3 = n - 3 > 0 ? n - 3 : 0;
    if (t == 0) base = atomicAdd(pair_count, n1 + n2 + n3);   // one reservation per class
    __syncthreads();
    const int b = base;
    for (int p = t; p < n1; p += 256) pairs[b + p]           = make_int2(idxs[p], idxs[p + 1]);
    for (int p = t; p < n2; p += 256) pairs[b + n1 + p]      = make_int2(idxs[p], idxs[p + 2]);
    for (int p = t; p < n3; p += 256) pairs[b + n1 + n2 + p] = make_int2(idxs[p], idxs[p + 3]);
}

// ---------- kernel C: triangular MFMA X.X^T + fused dist/exp/mask, row+col reduce ----------
// LDS: linear row-major [128][64] bf16 per tile, XOR-swizzled 16B octets:
//   phys(row, Q) = row*64 + (Q ^ (row&7))*8   (elements)
// Staged via global_load_lds with the swizzle pre-applied to the per-lane GLOBAL
// source address (rule #21: linear dest + inverse-swz source + swz on read).
__global__ __launch_bounds__(256)
void lneg_mfma(const u16* __restrict__ Xb, const int* __restrict__ tgt,
               const float* __restrict__ sqn, float* __restrict__ l_n) {
    // triangular tile index: z -> (bi, bj), bi <= bj
    int z = blockIdx.x;
    int bi = (int)((2 * NT + 1 - sqrtf((float)((2 * NT + 1) * (2 * NT + 1)) - 8.0f * (float)z)) * 0.5f);
    while (z <  bi * (2 * NT + 1 - bi) / 2) --bi;
    while (z >= (bi + 1) * (2 * NT - bi) / 2) ++bi;
    const int bj = bi + (z - bi * (2 * NT + 1 - bi) / 2);
    const int row0 = bi * BM, col0 = bj * BN;
    const bool offdiag = (bi != bj);

    __shared__ u16 As[2][BM * BK];   // 16 KB x2
    __shared__ u16 Bs[2][BN * BK];   // 16 KB x2
    const int t = threadIdx.x;
    const int w = t >> 6, l = t & 63;
    const int wr = w >> 1, wc = w & 1;       // wave quadrant: 64x64 output
    const int lc = l & 15, lg = l >> 4;
    const int swz = lc & 7;

    // staging decode for this lane (per instruction q): phys chunk pc = w*256+q*64+l
    // r = pc>>3, vq = pc&7, logical octet = vq ^ (r&7)
    f32x4 acc[4][4] = {};

#define STAGE(buf, kk)                                                                             \
    {                                                                                              \
        _Pragma("unroll")                                                                          \
        for (int q = 0; q < 4; ++q) {                                                              \
            int pc = w * 256 + q * 64 + l;                                                         \
            int r = pc >> 3, vq = pc & 7;                                                          \
            int ql = vq ^ (r & 7);                                                                 \
            const u16* ga = Xb + (size_t)(row0 + r) * D + (kk) + ql * 8;                           \
            const u16* gb = Xb + (size_t)(col0 + r) * D + (kk) + ql * 8;                           \
            u16* la = &As[buf][(w * 256 + q * 64) * 8];                                            \
            u16* lb = &Bs[buf][(w * 256 + q * 64) * 8];                                            \
            __builtin_amdgcn_global_load_lds((const __attribute__((address_space(1))) unsigned int*)ga, \
                                             (__attribute__((address_space(3))) unsigned int*)la, 16, 0, 0); \
            __builtin_amdgcn_global_load_lds((const __attribute__((address_space(1))) unsigned int*)gb, \
                                             (__attribute__((address_space(3))) unsigned int*)lb, 16, 0, 0); \
        }                                                                                          \
    }

    STAGE(0, 0)
    __syncthreads();

    for (int kt = 0; kt < D / BK; ++kt) {
        const int cur = kt & 1;
        if (kt < D / BK - 1) STAGE(cur ^ 1, (kt + 1) * BK)

        bf16x8 af[4][2], bfr[4][2];
        #pragma unroll
        for (int fm = 0; fm < 4; ++fm)
            #pragma unroll
            for (int ks = 0; ks < 2; ++ks) {
                int row = wr * 64 + fm * 16 + lc;
                int Q   = ks * 4 + lg;
                af[fm][ks] = *reinterpret_cast<const bf16x8*>(&As[cur][row * 64 + ((Q ^ swz) * 8)]);
            }
        #pragma unroll
        for (int fn = 0; fn < 4; ++fn)
            #pragma unroll
            for (int ks = 0; ks < 2; ++ks) {
                int col = wc * 64 + fn * 16 + lc;
                int Q   = ks * 4 + lg;
                bfr[fn][ks] = *reinterpret_cast<const bf16x8*>(&Bs[cur][col * 64 + ((Q ^ swz) * 8)]);
            }
        #pragma unroll
        for (int fm = 0; fm < 4; ++fm)
            #pragma unroll
            for (int fn = 0; fn < 4; ++fn) {
                acc[fm][fn] = __builtin_amdgcn_mfma_f32_16x16x32_bf16(af[fm][0], bfr[fn][0], acc[fm][fn], 0, 0, 0);
                acc[fm][fn] = __builtin_amdgcn_mfma_f32_16x16x32_bf16(af[fm][1], bfr[fn][1], acc[fm][fn], 0, 0, 0);
            }
        __syncthreads();   // drains next-tile loads; protects cur buf for overwrite
    }
#undef STAGE

    // epilogue: C layout col = l&15, row = (l>>4)*4 + reg  [guide m89]
    int tgj[4]; float sqj[4];
    #pragma unroll
    for (int fn = 0; fn < 4; ++fn) {
        int gj = col0 + wc * 64 + fn * 16 + lc;
        tgj[fn] = tgt[gj]; sqj[fn] = sqn[gj];
    }
    float csum[4] = {};
    #pragma unroll
    for (int fm = 0; fm < 4; ++fm) {
        #pragma unroll
        for (int r = 0; r < 4; ++r) {
            int gi = row0 + wr * 64 + fm * 16 + lg * 4 + r;
            float sqi = sqn[gi]; int tgi = tgt[gi];
            float rs = 0.f;
            #pragma unroll
            for (int fn = 0; fn < 4; ++fn) {
                float sq = sqi + sqj[fn] - 2.f * acc[fm][fn][r];
                sq = fmaxf(sq, 0.f);
                float dd = sq > 1e-12f ? sqrtf(sq) : 0.f;
                float e = (tgi != tgj[fn]) ? __expf(MARGIN - dd) : 0.f;
                rs += e;
                csum[fn] += e;
            }
            rs += __shfl_xor(rs, 1); rs += __shfl_xor(rs, 2);
            rs += __shfl_xor(rs, 4); rs += __shfl_xor(rs, 8);
            if (lc == 0) atomicAdd(&l_n[gi], rs);
        }
    }
    if (offdiag) {
        #pragma unroll
        for (int fn = 0; fn < 4; ++fn) {
            float s = csum[fn];
            s += __shfl_xor(s, 16); s += __shfl_xor(s, 32);
            if (lg == 0) atomicAdd(&l_n[col0 + wc * 64 + fn * 16 + lc], s);
        }
    }
}

// ---------- kernel D: grid-stride pair loss + fused finalize ----------
#define PL_BLOCKS 256
__global__ __launch_bounds__(256)
void pair_loss(const float* __restrict__ X, const float* __restrict__ sqn,
               const float* __restrict__ rown, const float* __restrict__ l_n,
               const int2* __restrict__ pairs, const int* __restrict__ pair_count,
               float* __restrict__ out) {
    const int t = threadIdx.x;
    const int lane = t & 63;
    const int np = *pair_count;
    const int wid0 = blockIdx.x * 4 + (t >> 6);
    float local = 0.f;
    for (int p = wid0; p < np; p += PL_BLOCKS * 4) {
        int2 pr = pairs[p];
        const float* xi = X + (size_t)pr.x * D + lane * 8;
        const float* xj = X + (size_t)pr.y * D + lane * 8;
        float4 a0 = *reinterpret_cast<const float4*>(xi);
        float4 a1 = *reinterpret_cast<const float4*>(xi + 4);
        float4 b0 = *reinterpret_cast<const float4*>(xj);
        float4 b1 = *reinterpret_cast<const float4*>(xj + 4);
        float s = a0.x * b0.x + a0.y * b0.y + a0.z * b0.z + a0.w * b0.w
                + a1.x * b1.x + a1.y * b1.y + a1.z * b1.z + a1.w * b1.w;
        #pragma unroll
        for (int off = 32; off; off >>= 1) s += __shfl_xor(s, off);
        if (lane == 0) {
            float sq = sqn[pr.x] + sqn[pr.y] - 2.f * s;
            sq = fmaxf(sq, 0.f);
            float dd = sq > 1e-12f ? sqrtf(sq) : 0.f;
            float ln = logf(l_n[pr.x] + l_n[pr.y]);
            float pl = fmaxf(ln + dd, 0.f);
            local += pl * pl;
        }
    }
    __shared__ float wsum[4];
    if (lane == 0) wsum[t >> 6] = local;
    __syncthreads();
    if (t == 0 && np > 0)
        atomicAdd(out, (wsum[0] + wsum[1] + wsum[2] + wsum[3]) / (float)np);

    // block 0 also folds in the L2 term
    if (blockIdx.x == 0) {
        float s = 0.f;
        for (int i = t; i < N; i += 256) s += rown[i];
        #pragma unroll
        for (int off = 32; off; off >>= 1) s += __shfl_xor(s, off);
        __shared__ float nsum[4];
        if (lane == 0) nsum[t >> 6] = s;
        __syncthreads();
        if (t == 0)
            atomicAdd(out, L2_REG * (nsum[0] + nsum[1] + nsum[2] + nsum[3]) / (float)N);
    }
}

extern "C" void kernel_launch(void* const* d_in, const int* in_sizes, int n_in,
                              void* d_out, int out_size, void* d_ws, size_t ws_size,
                              hipStream_t stream) {
    const float* X   = (const float*)d_in[0];
    const int*   tgt = (const int*)d_in[1];

    u16*   Xb = (u16*)d_ws;                                   // N*D bf16 = 4 MB
    float* fw = (float*)((char*)d_ws + (size_t)N * D * 2);
    float* sqn        = fw;                // N
    float* rown       = fw + N;            // N
    float* l_n        = fw + 2 * N;        // N
    int*   pair_count = (int*)(fw + 3 * N);
    int2*  pairs      = (int2*)(fw + 3 * N + 2);              // MAXPAIRS int2

    prep<<<N / 4, 256, 0, stream>>>(X, Xb, sqn, rown, l_n, pair_count);
    build_pairs<<<NCLASS, 256, 0, stream>>>(tgt, pairs, pair_count, (float*)d_out);
    lneg_mfma<<<NT * (NT + 1) / 2, 256, 0, stream>>>(Xb, tgt, sqn, l_n);
    pair_loss<<<PL_BLOCKS, 256, 0, stream>>>(X, sqn, rown, l_n, pairs, pair_count, (float*)d_out);
}